// Round 11
// baseline (119.884 us; speedup 1.0000x reference)
//
#include <hip/hip_runtime.h>
#include <hip/hip_bf16.h>
#include <math.h>

#define DIM 256
#define BB 1024
#define KK 128
#define PITCH 264   // bf16 elements per LDS row: 528 B, 16B-aligned rows

typedef __attribute__((ext_vector_type(8))) short short8;
typedef __attribute__((ext_vector_type(4))) float float4v;

__device__ __forceinline__ float dot4(const float4 a, const float4 b) {
    return a.x*b.x + a.y*b.y + a.z*b.z + a.w*b.w;
}

// two f32 -> packed bf16x2 bits (RNE); lowers to v_cvt_pk_bf16_f32
__device__ __forceinline__ unsigned bf2bits(float a, float b) {
    float2 t; t.x = a; t.y = b;
    __hip_bfloat162 h = __float22bfloat162_rn(t);
    unsigned u; __builtin_memcpy(&u, &h, 4);
    return u;
}

// x + row_ror<CTRL>(x): VALU-only cross-lane add within a 16-lane DPP row.
template<int CTRL>
__device__ __forceinline__ float addror(float x) {
    int r = __builtin_amdgcn_update_dpp(0, __float_as_int(x), CTRL, 0xF, 0xF, true);
    return x + __int_as_float(r);
}
__device__ __forceinline__ float sum16dpp(float x) {
    x = addror<0x121>(x);   // row_ror:1
    x = addror<0x122>(x);   // row_ror:2
    x = addror<0x124>(x);   // row_ror:4
    x = addror<0x128>(x);   // row_ror:8
    return x;
}
__device__ __forceinline__ float sum64dpp(float x) {
    x = sum16dpp(x);
    x += __shfl_xor(x, 16);
    x += __shfl_xor(x, 32);
    return x;
}

// One block per batch element. 512 threads = 8 waves — the proven
// spill-free envelope (VGPR=64). LDS 77.8 KB -> 2 blocks/CU.
__global__ __launch_bounds__(512, 4) void fused_main(
    const float* __restrict__ feature,
    const float* __restrict__ text,
    const float* __restrict__ virt,
    const float* __restrict__ gumbel,
    const int*   __restrict__ ego,
    const int*   __restrict__ adj,
    float*       __restrict__ score_raw)
{
    __shared__ unsigned short tbs[KK * PITCH];   // 67584 B
    __shared__ float fpart[4][DIM];              // 4096 B (pair-combined f_diff)
    __shared__ float rowpart[KK][8];             // 4096 B ({s,a2,a3,fia} x 2 halves)
    __shared__ unsigned abits[KK][4];            // 2048 B (adj bitmask per row)
    __shared__ float spart[2];

    const int b    = blockIdx.x;
    const int tid  = threadIdx.x;
    const int wave = tid >> 6;
    const int lane = tid & 63;

    const float4 vm = ((const float4*)virt)[lane];
    const float vv2 = sum64dpp(dot4(vm, vm));    // ||v||^2, all lanes

    const int* ego_b = ego + b * KK;
    const int* adj_b = adj + (size_t)b * KK * KK;
    const int  base  = wave * 16;

    float4 fdv = make_float4(0.f, 0.f, 0.f, 0.f);

    // ---- Phase A: wave owns rows base..base+15; 4 rows per bt iteration.
    // adj rows read as coalesced cached dword loads (lane = column) and
    // packed to bitmasks via __ballot: bit l = column l (halves at +64).
    #pragma unroll
    for (int bt = 0; bt < 4; ++bt) {
        const int r0 = base + bt * 4;
        const int e0i = ego_b[r0 + 0], e1i = ego_b[r0 + 1];
        const int e2i = ego_b[r0 + 2], e3i = ego_b[r0 + 3];
        const float4 T0 = ((const float4*)(text + (size_t)e0i * DIM))[lane];
        const float4 T1 = ((const float4*)(text + (size_t)e1i * DIM))[lane];
        const float4 T2 = ((const float4*)(text + (size_t)e2i * DIM))[lane];
        const float4 T3 = ((const float4*)(text + (size_t)e3i * DIM))[lane];
        const float4 F0 = ((const float4*)(feature + (size_t)e0i * DIM))[lane];
        const float4 F1 = ((const float4*)(feature + (size_t)e1i * DIM))[lane];
        const float4 F2 = ((const float4*)(feature + (size_t)e2i * DIM))[lane];
        const float4 F3 = ((const float4*)(feature + (size_t)e3i * DIM))[lane];
        // adj: 8 coalesced dword loads (256B each), normal caching
        const int a0l = adj_b[(size_t)(r0 + 0) * KK + lane];
        const int a0h = adj_b[(size_t)(r0 + 0) * KK + 64 + lane];
        const int a1l = adj_b[(size_t)(r0 + 1) * KK + lane];
        const int a1h = adj_b[(size_t)(r0 + 1) * KK + 64 + lane];
        const int a2l = adj_b[(size_t)(r0 + 2) * KK + lane];
        const int a2h = adj_b[(size_t)(r0 + 2) * KK + 64 + lane];
        const int a3l = adj_b[(size_t)(r0 + 3) * KK + lane];
        const int a3h = adj_b[(size_t)(r0 + 3) * KK + 64 + lane];

        float st0 = dot4(T0, T0), sv0 = dot4(T0, vm), sf0 = dot4(F0, F0);
        float st1 = dot4(T1, T1), sv1 = dot4(T1, vm), sf1 = dot4(F1, F1);
        float st2 = dot4(T2, T2), sv2 = dot4(T2, vm), sf2 = dot4(F2, F2);
        float st3 = dot4(T3, T3), sv3 = dot4(T3, vm), sf3 = dot4(F3, F3);

        st0 = sum64dpp(st0); sv0 = sum64dpp(sv0); sf0 = sum64dpp(sf0);
        st1 = sum64dpp(st1); sv1 = sum64dpp(sv1); sf1 = sum64dpp(sf1);
        st2 = sum64dpp(st2); sv2 = sum64dpp(sv2); sf2 = sum64dpp(sf2);
        st3 = sum64dpp(st3); sv3 = sum64dpp(sv3); sf3 = sum64dpp(sf3);

        // pack adj bits: ballot bit l == column l of the half-row
        const unsigned long long m0l = __ballot(a0l != 0);
        const unsigned long long m0h = __ballot(a0h != 0);
        const unsigned long long m1l = __ballot(a1l != 0);
        const unsigned long long m1h = __ballot(a1h != 0);
        const unsigned long long m2l = __ballot(a2l != 0);
        const unsigned long long m2h = __ballot(a2h != 0);
        const unsigned long long m3l = __ballot(a3l != 0);
        const unsigned long long m3h = __ballot(a3h != 0);
        if (lane == 0) {
            uint4 w;
            w.x = (unsigned)m0l; w.y = (unsigned)(m0l >> 32);
            w.z = (unsigned)m0h; w.w = (unsigned)(m0h >> 32);
            *(uint4*)&abits[r0 + 0][0] = w;
            w.x = (unsigned)m1l; w.y = (unsigned)(m1l >> 32);
            w.z = (unsigned)m1h; w.w = (unsigned)(m1h >> 32);
            *(uint4*)&abits[r0 + 1][0] = w;
            w.x = (unsigned)m2l; w.y = (unsigned)(m2l >> 32);
            w.z = (unsigned)m2h; w.w = (unsigned)(m2h >> 32);
            *(uint4*)&abits[r0 + 2][0] = w;
            w.x = (unsigned)m3l; w.y = (unsigned)(m3l >> 32);
            w.z = (unsigned)m3h; w.w = (unsigned)(m3h >> 32);
            *(uint4*)&abits[r0 + 3][0] = w;
        }

        // ||emb - v||^2 = 1 + ||v||^2 - 2 (t.v)/||t||
        #define NORMROW(Tj, Fj, stj, sfj, svj, ROW)                              \
        {                                                                        \
            const float inv_ne = __builtin_amdgcn_rsqf(fmaxf(stj, 1e-24f));      \
            const float inv_nf = __builtin_amdgcn_rsqf(fmaxf(sfj, 1e-24f));      \
            const float nw2    = fmaxf(1.f + vv2 - 2.f * svj * inv_ne, 1e-24f);  \
            const float inv_nt = __builtin_amdgcn_rsqf(nw2);                     \
            const float e0 = Tj.x * inv_ne, e1 = Tj.y * inv_ne;                  \
            const float e2 = Tj.z * inv_ne, e3 = Tj.w * inv_ne;                  \
            fdv.x += Fj.x * inv_nf - e0;  fdv.y += Fj.y * inv_nf - e1;           \
            fdv.z += Fj.z * inv_nf - e2;  fdv.w += Fj.w * inv_nf - e3;           \
            uint2 pk;                                                            \
            pk.x = bf2bits((e0 - vm.x) * inv_nt, (e1 - vm.y) * inv_nt);          \
            pk.y = bf2bits((e2 - vm.z) * inv_nt, (e3 - vm.w) * inv_nt);          \
            *(uint2*)&tbs[(ROW) * PITCH + 4 * lane] = pk;                        \
        }
        NORMROW(T0, F0, st0, sf0, sv0, r0 + 0)
        NORMROW(T1, F1, st1, sf1, sv1, r0 + 1)
        NORMROW(T2, F2, st2, sf2, sv2, r0 + 2)
        NORMROW(T3, F3, st3, sf3, sv3, r0 + 3)
        #undef NORMROW
    }
    // f_diff pair combine: odd waves park, even waves add after barrier
    if (wave & 1) *(float4*)&fpart[wave >> 1][4 * lane] = fdv;

    __syncthreads();

    if (!(wave & 1)) {
        float4 o = *(float4*)&fpart[wave >> 1][4 * lane];
        o.x += fdv.x; o.y += fdv.y; o.z += fdv.z; o.w += fdv.w;
        *(float4*)&fpart[wave >> 1][4 * lane] = o;
    }

    // ---- Phase B: wave = 16-row strip; columns in two half passes.
    const int g = lane >> 4;   // 0..3
    const int c = lane & 15;
    const float* grb = gumbel + ((size_t)b * KK + base + g * 4) * KK + c;

    #pragma unroll
    for (int h = 0; h < 2; ++h) {
        // hoist this half's 16 gumbel values: issued before the MFMA loop,
        // ~400cy of MFMA/ds_read cover before first use
        float gvv[16];
        #pragma unroll
        for (int r = 0; r < 4; ++r) {
            #pragma unroll
            for (int t = 0; t < 4; ++t)
                gvv[r * 4 + t] =
                    __builtin_nontemporal_load(grb + r * KK + h * 64 + t * 16);
        }

        float4v acc[4];
        #pragma unroll
        for (int t = 0; t < 4; ++t) acc[t] = (float4v){0.f, 0.f, 0.f, 0.f};

        #pragma unroll
        for (int q = 0; q < 8; ++q) {
            const int dq = q * 32 + g * 8;
            const short8 afr = *(const short8*)&tbs[(base + c) * PITCH + dq];
            #pragma unroll
            for (int t = 0; t < 4; ++t) {
                const short8 bfr = *(const short8*)&tbs[(h * 64 + t * 16 + c) * PITCH + dq];
                acc[t] = __builtin_amdgcn_mfma_f32_16x16x32_bf16(afr, bfr, acc[t], 0, 0, 0);
            }
        }

        // softmax partials per row; adj bits from LDS (uniform b64 broadcast).
        // No max-subtract needed: |sim-0.5+gumbel| <= ~14, fp32-safe.
        #pragma unroll
        for (int r = 0; r < 4; ++r) {
            const uint2 aw = *(const uint2*)&abits[base + g * 4 + r][h * 2];

            float s = 0.f, a2 = 0.f, a3 = 0.f;
            #pragma unroll
            for (int t = 0; t < 4; ++t) {
                const float et = __expf(acc[t][r] - 0.5f + gvv[r * 4 + t]);
                const unsigned w  = (t < 2) ? aw.x : aw.y;
                const unsigned bit = (w >> ((t & 1) * 16 + c)) & 1u;
                s  += et;
                a3 += et * et;
                a2 += bit ? et : 0.f;
            }
            s  = sum16dpp(s);
            a2 = sum16dpp(a2);
            a3 = sum16dpp(a3);
            const float fia = (float)(__popc(aw.x) + __popc(aw.y));  // uniform

            if (c == 0) {
                float4 pk4; pk4.x = s; pk4.y = a2; pk4.z = a3; pk4.w = fia;
                *(float4*)&rowpart[base + g * 4 + r][h * 4] = pk4;
            }
        }
    }

    __syncthreads();

    // combine halves: threads 0..127 own one row each
    if (tid < KK) {
        const float4 pa = *(const float4*)&rowpart[tid][0];
        const float4 pb = *(const float4*)&rowpart[tid][4];
        const float s   = pa.x + pb.x;
        const float a2  = pa.y + pb.y;
        const float a3  = pa.z + pb.z;
        const float fia = pa.w + pb.w;
        // sum (adj-p)^2 = sum(adj) - invS*(2 sum(adj e) - invS sum(e^2))
        const float invS = __builtin_amdgcn_rcpf(s);
        float sq = sqrtf(fmaxf(fia - invS * (2.f * a2 - invS * a3), 0.f));
        sq = sum64dpp(sq);
        if (lane == 0) spart[wave] = sq;   // wave 0 or 1
    }

    __syncthreads();

    if (wave == 0) {
        float4 d = make_float4(0.f, 0.f, 0.f, 0.f);
        #pragma unroll
        for (int j = 0; j < 4; ++j) {
            const float4 p = *(const float4*)&fpart[j][4 * lane];
            d.x += p.x; d.y += p.y; d.z += p.z; d.w += p.w;
        }
        const float inv = 1.f / 128.f;
        d.x *= inv; d.y *= inv; d.z *= inv; d.w *= inv;
        const float q2 = sum64dpp(dot4(d, d));
        if (lane == 0)
            score_raw[b] = (spart[0] + spart[1]) * (1.f / 128.f) + sqrtf(q2);
    }
}

__global__ __launch_bounds__(1024) void finalize(
    const float* __restrict__ score_raw,
    const int*   __restrict__ label,
    float*       __restrict__ out)
{
    __shared__ float wmin[16], wmax[16], wsum[16];
    const int tid = threadIdx.x;
    const float s = score_raw[tid];
    float mn = s, mx = s;
    #pragma unroll
    for (int m = 1; m < 64; m <<= 1) {
        mn = fminf(mn, __shfl_xor(mn, m));
        mx = fmaxf(mx, __shfl_xor(mx, m));
    }
    if ((tid & 63) == 0) { wmin[tid >> 6] = mn; wmax[tid >> 6] = mx; }
    __syncthreads();
    float gmn = wmin[0], gmx = wmax[0];
    #pragma unroll
    for (int w = 1; w < 16; ++w) {
        gmn = fminf(gmn, wmin[w]);
        gmx = fmaxf(gmx, wmax[w]);
    }
    const float score = (s - gmn) / (gmx - gmn);
    out[tid] = score;

    const float y  = (float)label[tid];
    const float sc = fminf(fmaxf(score, 1e-7f), 1.f - 1e-7f);
    float term = -(y * logf(sc) + (1.f - y) * log1pf(-sc));
    #pragma unroll
    for (int m = 1; m < 64; m <<= 1) term += __shfl_xor(term, m);
    if ((tid & 63) == 0) wsum[tid >> 6] = term;
    __syncthreads();
    if (tid == 0) {
        float tot = 0.f;
        #pragma unroll
        for (int w = 0; w < 16; ++w) tot += wsum[w];
        out[BB] = tot / (1024.f * 1024.f);
    }
}

extern "C" void kernel_launch(void* const* d_in, const int* in_sizes, int n_in,
                              void* d_out, int out_size, void* d_ws, size_t ws_size,
                              hipStream_t stream) {
    const float* feature = (const float*)d_in[0];
    const float* text    = (const float*)d_in[1];
    const float* virt    = (const float*)d_in[2];
    const float* gumbel  = (const float*)d_in[3];
    const int*   ego     = (const int*)d_in[4];
    const int*   adj     = (const int*)d_in[5];
    const int*   label   = (const int*)d_in[6];
    float* out       = (float*)d_out;
    float* score_raw = (float*)d_ws;

    fused_main<<<BB, 512, 0, stream>>>(feature, text, virt, gumbel, ego, adj, score_raw);
    finalize<<<1, 1024, 0, stream>>>(score_raw, label, out);
}

// Round 12
// 68.138 us; speedup vs baseline: 1.7594x; 1.7594x over previous
//
#include <hip/hip_runtime.h>
#include <hip/hip_bf16.h>
#include <math.h>

#define DIM 256
#define BB 1024
#define KK 128
#define PITCH 264   // bf16 elements per LDS row: 528 B, 16B-aligned rows

typedef __attribute__((ext_vector_type(8))) short short8;
typedef __attribute__((ext_vector_type(4))) float float4v;

__device__ __forceinline__ float dot4(const float4 a, const float4 b) {
    return a.x*b.x + a.y*b.y + a.z*b.z + a.w*b.w;
}

// two f32 -> packed bf16x2 bits (RNE); lowers to v_cvt_pk_bf16_f32
__device__ __forceinline__ unsigned bf2bits(float a, float b) {
    float2 t; t.x = a; t.y = b;
    __hip_bfloat162 h = __float22bfloat162_rn(t);
    unsigned u; __builtin_memcpy(&u, &h, 4);
    return u;
}

// x + row_ror<CTRL>(x): VALU-only cross-lane add within a 16-lane DPP row.
template<int CTRL>
__device__ __forceinline__ float addror(float x) {
    int r = __builtin_amdgcn_update_dpp(0, __float_as_int(x), CTRL, 0xF, 0xF, true);
    return x + __int_as_float(r);
}
__device__ __forceinline__ float sum16dpp(float x) {
    x = addror<0x121>(x);   // row_ror:1
    x = addror<0x122>(x);   // row_ror:2
    x = addror<0x124>(x);   // row_ror:4
    x = addror<0x128>(x);   // row_ror:8
    return x;
}
__device__ __forceinline__ float sum64dpp(float x) {
    x = sum16dpp(x);
    x += __shfl_xor(x, 16);
    x += __shfl_xor(x, 32);
    return x;
}

// One block per batch element. 512 threads = 8 waves — the proven
// spill-free envelope (VGPR=64). Phase A is byte-identical to the R8
// champion (zero spare registers there); phase B adds gumbel/adj hoisting.
__global__ __launch_bounds__(512, 4) void fused_main(
    const float* __restrict__ feature,
    const float* __restrict__ text,
    const float* __restrict__ virt,
    const float* __restrict__ gumbel,
    const int*   __restrict__ ego,
    const int*   __restrict__ adj,
    float*       __restrict__ score_raw)
{
    __shared__ unsigned short tbs[KK * PITCH];   // 67584 B
    __shared__ float fpart[8][DIM];              // 8192 B
    __shared__ float rowpart[KK][8];             // 4096 B ({s,a2,a3,fia} x 2 halves)
    __shared__ float spart[2];

    const int b    = blockIdx.x;
    const int tid  = threadIdx.x;
    const int wave = tid >> 6;
    const int lane = tid & 63;

    const float4 vm = ((const float4*)virt)[lane];
    const float vv2 = sum64dpp(dot4(vm, vm));    // ||v||^2, all lanes

    const int* ego_b = ego + b * KK;
    const int  base  = wave * 16;

    float4 fdv = make_float4(0.f, 0.f, 0.f, 0.f);

    // ---- Phase A (identical to R8): 4 rows per bt, 8 loads in flight,
    // 12 independent DPP reduction chains.
    #pragma unroll
    for (int bt = 0; bt < 4; ++bt) {
        const int r0 = base + bt * 4;
        const int e0i = ego_b[r0 + 0], e1i = ego_b[r0 + 1];
        const int e2i = ego_b[r0 + 2], e3i = ego_b[r0 + 3];
        const float4 T0 = ((const float4*)(text + (size_t)e0i * DIM))[lane];
        const float4 T1 = ((const float4*)(text + (size_t)e1i * DIM))[lane];
        const float4 T2 = ((const float4*)(text + (size_t)e2i * DIM))[lane];
        const float4 T3 = ((const float4*)(text + (size_t)e3i * DIM))[lane];
        const float4 F0 = ((const float4*)(feature + (size_t)e0i * DIM))[lane];
        const float4 F1 = ((const float4*)(feature + (size_t)e1i * DIM))[lane];
        const float4 F2 = ((const float4*)(feature + (size_t)e2i * DIM))[lane];
        const float4 F3 = ((const float4*)(feature + (size_t)e3i * DIM))[lane];

        float st0 = dot4(T0, T0), sv0 = dot4(T0, vm), sf0 = dot4(F0, F0);
        float st1 = dot4(T1, T1), sv1 = dot4(T1, vm), sf1 = dot4(F1, F1);
        float st2 = dot4(T2, T2), sv2 = dot4(T2, vm), sf2 = dot4(F2, F2);
        float st3 = dot4(T3, T3), sv3 = dot4(T3, vm), sf3 = dot4(F3, F3);

        st0 = sum64dpp(st0); sv0 = sum64dpp(sv0); sf0 = sum64dpp(sf0);
        st1 = sum64dpp(st1); sv1 = sum64dpp(sv1); sf1 = sum64dpp(sf1);
        st2 = sum64dpp(st2); sv2 = sum64dpp(sv2); sf2 = sum64dpp(sf2);
        st3 = sum64dpp(st3); sv3 = sum64dpp(sv3); sf3 = sum64dpp(sf3);

        // ||emb - v||^2 = 1 + ||v||^2 - 2 (t.v)/||t||
        #define NORMROW(Tj, Fj, stj, sfj, svj, ROW)                              \
        {                                                                        \
            const float inv_ne = __builtin_amdgcn_rsqf(fmaxf(stj, 1e-24f));      \
            const float inv_nf = __builtin_amdgcn_rsqf(fmaxf(sfj, 1e-24f));      \
            const float nw2    = fmaxf(1.f + vv2 - 2.f * svj * inv_ne, 1e-24f);  \
            const float inv_nt = __builtin_amdgcn_rsqf(nw2);                     \
            const float e0 = Tj.x * inv_ne, e1 = Tj.y * inv_ne;                  \
            const float e2 = Tj.z * inv_ne, e3 = Tj.w * inv_ne;                  \
            fdv.x += Fj.x * inv_nf - e0;  fdv.y += Fj.y * inv_nf - e1;           \
            fdv.z += Fj.z * inv_nf - e2;  fdv.w += Fj.w * inv_nf - e3;           \
            uint2 pk;                                                            \
            pk.x = bf2bits((e0 - vm.x) * inv_nt, (e1 - vm.y) * inv_nt);          \
            pk.y = bf2bits((e2 - vm.z) * inv_nt, (e3 - vm.w) * inv_nt);          \
            *(uint2*)&tbs[(ROW) * PITCH + 4 * lane] = pk;                        \
        }
        NORMROW(T0, F0, st0, sf0, sv0, r0 + 0)
        NORMROW(T1, F1, st1, sf1, sv1, r0 + 1)
        NORMROW(T2, F2, st2, sf2, sv2, r0 + 2)
        NORMROW(T3, F3, st3, sf3, sv3, r0 + 3)
        #undef NORMROW
    }
    *(float4*)&fpart[wave][4 * lane] = fdv;

    __syncthreads();

    // ---- Phase B: wave = 16-row strip; columns in two half passes.
    const int g = lane >> 4;   // 0..3
    const int c = lane & 15;
    const float* grb = gumbel + ((size_t)b * KK + base + g * 4) * KK + c;
    const int*   arb = adj    + ((size_t)b * KK + base + g * 4) * KK + c;

    #pragma unroll
    for (int h = 0; h < 2; ++h) {
        // hoist this half's 16 gumbel values + row 0's adj: issued before
        // the MFMA loop, ~400cy of MFMA/ds_read cover before first use
        float gvv[16];
        #pragma unroll
        for (int r = 0; r < 4; ++r) {
            #pragma unroll
            for (int t = 0; t < 4; ++t)
                gvv[r * 4 + t] =
                    __builtin_nontemporal_load(grb + r * KK + h * 64 + t * 16);
        }
        int a_in[4];
        #pragma unroll
        for (int t = 0; t < 4; ++t)
            a_in[t] = __builtin_nontemporal_load(arb + h * 64 + t * 16);

        float4v acc[4];
        #pragma unroll
        for (int t = 0; t < 4; ++t) acc[t] = (float4v){0.f, 0.f, 0.f, 0.f};

        #pragma unroll
        for (int q = 0; q < 8; ++q) {
            const int dq = q * 32 + g * 8;
            const short8 afr = *(const short8*)&tbs[(base + c) * PITCH + dq];
            #pragma unroll
            for (int t = 0; t < 4; ++t) {
                const short8 bfr = *(const short8*)&tbs[(h * 64 + t * 16 + c) * PITCH + dq];
                acc[t] = __builtin_amdgcn_mfma_f32_16x16x32_bf16(afr, bfr, acc[t], 0, 0, 0);
            }
        }

        // softmax partials per row; adj with 1-row lookahead (covered by
        // the previous row's VALU work). No max-subtract: |vt|<=~14, fp32-safe.
        #pragma unroll
        for (int r = 0; r < 4; ++r) {
            int av[4];
            #pragma unroll
            for (int t = 0; t < 4; ++t) av[t] = a_in[t];
            if (r < 3) {
                #pragma unroll
                for (int t = 0; t < 4; ++t)
                    a_in[t] = __builtin_nontemporal_load(
                        arb + (r + 1) * KK + h * 64 + t * 16);
            }

            float s = 0.f, a2 = 0.f, a3 = 0.f, fia = 0.f;
            #pragma unroll
            for (int t = 0; t < 4; ++t) {
                const float et = __expf(acc[t][r] - 0.5f + gvv[r * 4 + t]);
                s   += et;
                a3  += et * et;
                a2  += av[t] ? et : 0.f;
                fia += av[t] ? 1.f : 0.f;
            }
            s   = sum16dpp(s);
            a2  = sum16dpp(a2);
            a3  = sum16dpp(a3);
            fia = sum16dpp(fia);

            if (c == 0) {
                float4 pk4; pk4.x = s; pk4.y = a2; pk4.z = a3; pk4.w = fia;
                *(float4*)&rowpart[base + g * 4 + r][h * 4] = pk4;
            }
        }
    }

    __syncthreads();

    // combine halves: threads 0..127 own one row each
    if (tid < KK) {
        const float4 pa = *(const float4*)&rowpart[tid][0];
        const float4 pb = *(const float4*)&rowpart[tid][4];
        const float s   = pa.x + pb.x;
        const float a2  = pa.y + pb.y;
        const float a3  = pa.z + pb.z;
        const float fia = pa.w + pb.w;
        // sum (adj-p)^2 = sum(adj) - invS*(2 sum(adj e) - invS sum(e^2))
        const float invS = __builtin_amdgcn_rcpf(s);
        float sq = sqrtf(fmaxf(fia - invS * (2.f * a2 - invS * a3), 0.f));
        sq = sum64dpp(sq);
        if (lane == 0) spart[wave] = sq;   // wave 0 or 1
    }

    __syncthreads();

    if (wave == 0) {
        float4 d = make_float4(0.f, 0.f, 0.f, 0.f);
        #pragma unroll
        for (int j = 0; j < 8; ++j) {
            const float4 p = *(const float4*)&fpart[j][4 * lane];
            d.x += p.x; d.y += p.y; d.z += p.z; d.w += p.w;
        }
        const float inv = 1.f / 128.f;
        d.x *= inv; d.y *= inv; d.z *= inv; d.w *= inv;
        const float q2 = sum64dpp(dot4(d, d));
        if (lane == 0)
            score_raw[b] = (spart[0] + spart[1]) * (1.f / 128.f) + sqrtf(q2);
    }
}

__global__ __launch_bounds__(1024) void finalize(
    const float* __restrict__ score_raw,
    const int*   __restrict__ label,
    float*       __restrict__ out)
{
    __shared__ float wmin[16], wmax[16], wsum[16];
    const int tid = threadIdx.x;
    const float s = score_raw[tid];
    float mn = s, mx = s;
    #pragma unroll
    for (int m = 1; m < 64; m <<= 1) {
        mn = fminf(mn, __shfl_xor(mn, m));
        mx = fmaxf(mx, __shfl_xor(mx, m));
    }
    if ((tid & 63) == 0) { wmin[tid >> 6] = mn; wmax[tid >> 6] = mx; }
    __syncthreads();
    float gmn = wmin[0], gmx = wmax[0];
    #pragma unroll
    for (int w = 1; w < 16; ++w) {
        gmn = fminf(gmn, wmin[w]);
        gmx = fmaxf(gmx, wmax[w]);
    }
    const float score = (s - gmn) / (gmx - gmn);
    out[tid] = score;

    const float y  = (float)label[tid];
    const float sc = fminf(fmaxf(score, 1e-7f), 1.f - 1e-7f);
    float term = -(y * logf(sc) + (1.f - y) * log1pf(-sc));
    #pragma unroll
    for (int m = 1; m < 64; m <<= 1) term += __shfl_xor(term, m);
    if ((tid & 63) == 0) wsum[tid >> 6] = term;
    __syncthreads();
    if (tid == 0) {
        float tot = 0.f;
        #pragma unroll
        for (int w = 0; w < 16; ++w) tot += wsum[w];
        out[BB] = tot / (1024.f * 1024.f);
    }
}

extern "C" void kernel_launch(void* const* d_in, const int* in_sizes, int n_in,
                              void* d_out, int out_size, void* d_ws, size_t ws_size,
                              hipStream_t stream) {
    const float* feature = (const float*)d_in[0];
    const float* text    = (const float*)d_in[1];
    const float* virt    = (const float*)d_in[2];
    const float* gumbel  = (const float*)d_in[3];
    const int*   ego     = (const int*)d_in[4];
    const int*   adj     = (const int*)d_in[5];
    const int*   label   = (const int*)d_in[6];
    float* out       = (float*)d_out;
    float* score_raw = (float*)d_ws;

    fused_main<<<BB, 512, 0, stream>>>(feature, text, virt, gumbel, ego, adj, score_raw);
    finalize<<<1, 1024, 0, stream>>>(score_raw, label, out);
}